// Round 7
// baseline (193.223 us; speedup 1.0000x reference)
//
#include <hip/hip_runtime.h>
#include <stdint.h>

typedef _Float16 f16;
typedef _Float16 half8 __attribute__((ext_vector_type(8)));
typedef _Float16 half4 __attribute__((ext_vector_type(4)));
typedef _Float16 half2 __attribute__((ext_vector_type(2)));
typedef float floatx4 __attribute__((ext_vector_type(4)));

#define LOG2E 1.44269504088896340736f

// async global->LDS, 16B per lane. LDS dest must be wave-uniform base + lane*16.
__device__ __forceinline__ void async_cp16(const void* g, void* l) {
  __builtin_amdgcn_global_load_lds((const __attribute__((address_space(1))) void*)g,
                                   (__attribute__((address_space(3))) void*)l, 16, 0, 0);
}

// cvt_pkrtz returns __fp16x2; bit-cast to our _Float16-based half2.
__device__ __forceinline__ half2 pkrtz(float a, float b) {
  return __builtin_bit_cast(half2, __builtin_amdgcn_cvt_pkrtz(a, b));
}

// ---------------- fused prep: x transpose->fp16 + weight convert ----------------
__global__ __launch_bounds__(256) void k_prep(const float* __restrict__ x,
                                              f16* __restrict__ XT,
                                              const float* __restrict__ wqkv,
                                              const float* __restrict__ wproj,
                                              f16* __restrict__ WQ, f16* __restrict__ WP) {
  __shared__ f16 sT[64][72];
  const int bid = blockIdx.x;
  const int tid = threadIdx.x;
  if (bid < 576) {
    const int hw0 = (bid % 9) * 64, c0 = ((bid / 9) & 7) * 64, b = bid / 72;
    const int cc = tid >> 6, hwc = tid & 63;
    const float* xb = x + (size_t)b * 294912;
    for (int i = 0; i < 16; ++i) {
      int c = c0 + i * 4 + cc;
      sT[hwc][i * 4 + cc] = (f16)xb[c * 576 + hw0 + hwc];
    }
    __syncthreads();
    const int c_c = tid & 63, rr = tid >> 6;
    f16* xtb = XT + ((size_t)b * 576 + hw0) * 512 + c0;
    for (int j = 0; j < 16; ++j) {
      int r = j * 4 + rr;
      xtb[(size_t)r * 512 + c_c] = sT[r][c_c];
    }
  } else {
    const float SCALE_Q = 0.125f * LOG2E;
    const int total1 = 1536 * 512, total2 = 512 * 512;
    for (int idx = (bid - 576) * 256 + tid; idx < total1 + total2; idx += 128 * 256) {
      if (idx < total1) {
        int row = idx >> 9;
        float v = wqkv[idx];
        if ((row % 192) < 64) v *= SCALE_Q;
        WQ[idx] = (f16)v;
      } else {
        WP[idx - total1] = (f16)wproj[idx - total1];
      }
    }
  }
}

// ---------------- QKV GEMM: D[t][row] = XT[t][:] . WQ[row][:] ----------------
// Vh written KEY-INTERLEAVED within each 32-key group: position p = 2*(k&15) | (k>>4),
// so a 16B read at position quad*8 delivers keys {quad*4+r} x {grp0,grp1} — the
// k-slot permutation consumed consistently by k_attn's PV 16x16x32 (A and B agree).
__global__ __launch_bounds__(256) void k_qkv_gemm(const f16* __restrict__ XT,
                                                  const f16* __restrict__ WQ,
                                                  f16* __restrict__ Qh, f16* __restrict__ Kh,
                                                  f16* __restrict__ Vh) {
  const int t0 = blockIdx.x * 128, n0 = blockIdx.y * 128;
  __shared__ alignas(16) f16 smem[2 * 128 * 64];
  f16* sA = smem;
  f16* sB = smem + 128 * 64;
  const int tid = threadIdx.x;
  const int wave = tid >> 6, lane = tid & 63, quad = lane >> 4, l16 = lane & 15;
  const int msub = (wave & 1) * 64, nsub = (wave >> 1) * 64;
  const floatx4 fzero = {0.f, 0.f, 0.f, 0.f};
  floatx4 acc[4][4];
  for (int i = 0; i < 4; ++i)
    for (int j = 0; j < 4; ++j) acc[i][j] = fzero;

  for (int k0 = 0; k0 < 512; k0 += 64) {
    __syncthreads();
    for (int p = 0; p < 4; ++p) {
      int e = p * 256 + tid;
      int row = e >> 3, colb = e & 7;
      async_cp16((const char*)XT + ((size_t)(t0 + row) * 512 + k0 + colb * 8) * 2,
                 (char*)sA + e * 16);
      async_cp16((const char*)WQ + ((size_t)(n0 + row) * 512 + k0 + colb * 8) * 2,
                 (char*)sB + e * 16);
    }
    __syncthreads();
    for (int f = 0; f < 2; ++f) {
      half8 a[4], bfr[4];
      for (int ms = 0; ms < 4; ++ms)
        a[ms] = *(const half8*)&sA[(msub + ms * 16 + l16) * 64 + f * 32 + quad * 8];
      for (int ns = 0; ns < 4; ++ns)
        bfr[ns] = *(const half8*)&sB[(nsub + ns * 16 + l16) * 64 + f * 32 + quad * 8];
      for (int ms = 0; ms < 4; ++ms)
        for (int ns = 0; ns < 4; ++ns)
          acc[ms][ns] =
              __builtin_amdgcn_mfma_f32_16x16x32_f16(a[ms], bfr[ns], acc[ms][ns], 0, 0, 0);
    }
  }
  for (int ms = 0; ms < 4; ++ms) {
    int tbase = t0 + msub + ms * 16 + quad * 4;
    for (int ns = 0; ns < 4; ++ns) {
      int row = n0 + nsub + ns * 16 + l16;
      int h = row / 192, rr2 = row % 192;
      int sel = rr2 >> 6, d = rr2 & 63;
      if (sel == 2) continue;
      for (int r = 0; r < 4; ++r) {
        int t = tbase + r;
        int b = t / 576, hw = t % 576;
        int g = b >> 2, v = b & 3;
        int n = v * 576 + hw;
        int gh = g * 8 + h;
        f16 hv = (f16)acc[ms][ns][r];
        size_t idx = ((size_t)gh * 2304 + n) * 64 + d;
        if (sel == 0)
          Qh[idx] = hv;
        else
          Kh[idx] = hv;
      }
    }
  }
  const int r0 = n0 % 192;
  if (r0 != 0) {
    const int vloc = (r0 == 128) ? 0 : 64;
    const int h = (n0 + vloc) / 192;
    f16* sVT = smem;
    __syncthreads();
    if ((wave >> 1) == (vloc >> 6)) {
      for (int ms = 0; ms < 4; ++ms) {
        int tok = msub + ms * 16 + quad * 4;
        for (int ns = 0; ns < 4; ++ns) {
          int d = ns * 16 + l16;
          half4 hv;
          for (int r = 0; r < 4; ++r) hv[r] = (f16)acc[ms][ns][r];
          *(half4*)&sVT[d * 136 + tok] = hv;
        }
      }
    }
    __syncthreads();
    // interleaved V write: 32-token groups (576%32==0 -> no b-straddle)
    for (int pss = 0; pss < 4; ++pss) {
      int d = pss * 16 + (tid >> 4);
      int sub = tid & 15, gg = sub >> 2, u = sub & 3;
      int t = t0 + gg * 32;
      int b = t / 576, hw = t - b * 576;
      int gh = (b >> 2) * 8 + h, nb = (b & 3) * 576 + hw;
      half4 va = *(const half4*)&sVT[d * 136 + gg * 32 + u * 4];
      half4 vb2 = *(const half4*)&sVT[d * 136 + gg * 32 + 16 + u * 4];
      half8 w = __builtin_shufflevector(va, vb2, 0, 4, 1, 5, 2, 6, 3, 7);
      *(half8*)(Vh + (size_t)gh * 147456 + (size_t)d * 2304 + nb + u * 8) = w;
    }
  }
}

// ---------------- flash attention: 48 queries/block, 6 waves, key-split 2-way ----
// grid = 48 x 16 = 768 blocks = exactly 3/CU, 18 waves/CU uniform.
// K: LDS-staged (swizzled, dbuf, barrier/kt). V: DIRECT GLOBAL with REGISTER
// DOUBLE-BUFFER — V for tile kt+1 is issued before tile kt's compute (statically
// named vA/vB, x2-unrolled loop), so L2 latency hides under a full phase and the
// pre-barrier vmcnt(0) drain completes it at the barrier. launch_bounds (384,4)
// leaves VGPR room (~80 live) so the scheduler cannot sink the loads to their use
// (R6 failure mode: VGPR=32 -> loads sunk -> raw latency exposed under lockstep).
__global__ __launch_bounds__(384, 4) void k_attn(const f16* __restrict__ Qh,
                                                 const f16* __restrict__ Kh,
                                                 const f16* __restrict__ Vh,
                                                 f16* __restrict__ AOT) {
  const int mt = blockIdx.x, gh = blockIdx.y;
  const int m0 = mt * 48;
  const int g = gh >> 3, h = gh & 7;
  const f16* Qg = Qh + (size_t)gh * 147456;  // [n][d]
  const f16* Kg = Kh + (size_t)gh * 147456;  // [n][d]
  const f16* Vg = Vh + (size_t)gh * 147456;  // [d][n'] key-interleaved
  __shared__ alignas(16) f16 smem[8192];     // 16 KB: sK[2 str][2 buf][32*64]
  f16* sK = smem;
  const int tid = threadIdx.x;
  const int wave = tid >> 6, lane = tid & 63, quad = lane >> 4, l16 = lane & 15;
  const int str = wave & 1, qgrp = wave >> 1;
  const floatx4 fzero = {0.f, 0.f, 0.f, 0.f};
  const int sw = l16 & 7;
  const half2 one2 = {(f16)1.f, (f16)1.f};

  // stage one 32-key K tile for both streams (512 cp16 units over 384 threads)
  auto stage_k = [&](int ktile, int buf) {
#pragma unroll
    for (int p = 0; p < 2; ++p) {
      int idx = p * 384 + tid;
      if (idx < 512) {
        int st = idx >> 8, unit = idx & 255;
        int row = unit >> 3, cb = unit & 7;
        async_cp16(
            Kg + (size_t)(st * 1152 + ktile * 32 + row) * 64 + ((cb ^ (row & 7)) << 3),
            (char*)(sK + (st * 2 + buf) * 2048) + unit * 16);
      }
    }
  };

  const f16* Vbase = Vg + str * 1152;
  auto loadV = [&](int kt, half8 (&vb)[4]) {
    const f16* vp = Vbase + kt * 32;
#pragma unroll
    for (int dt = 0; dt < 4; ++dt)
      vb[dt] = *(const half8*)(vp + (size_t)(dt * 16 + l16) * 2304 + quad * 8);
  };

  // Q direct to registers (A/B-frag: m=l16, k=quad*8+j / +32)
  half8 qa[2];
  {
    int qrow = m0 + qgrp * 16 + l16;
    qa[0] = *(const half8*)(Qg + (size_t)qrow * 64 + quad * 8);
    qa[1] = *(const half8*)(Qg + (size_t)qrow * 64 + 32 + quad * 8);
  }

  float l_lane = 0.f;
  floatx4 o[4];
  for (int dt = 0; dt < 4; ++dt) o[dt] = fzero;

  // one QK->softmax->PV phase on K buffer bK with V fragments vb
  auto qk_pv = [&](const f16* bK, const half8 (&vb)[4]) {
    floatx4 ta, tb;
    {
      half8 k0 = *(const half8*)&bK[l16 * 64 + ((quad ^ sw) << 3)];
      half8 k1 = *(const half8*)&bK[l16 * 64 + (((4 + quad) ^ sw) << 3)];
      ta = __builtin_amdgcn_mfma_f32_16x16x32_f16(k0, qa[0], fzero, 0, 0, 0);
      ta = __builtin_amdgcn_mfma_f32_16x16x32_f16(k1, qa[1], ta, 0, 0, 0);
    }
    {
      half8 k0 = *(const half8*)&bK[(16 + l16) * 64 + ((quad ^ sw) << 3)];
      half8 k1 = *(const half8*)&bK[(16 + l16) * 64 + (((4 + quad) ^ sw) << 3)];
      tb = __builtin_amdgcn_mfma_f32_16x16x32_f16(k0, qa[0], fzero, 0, 0, 0);
      tb = __builtin_amdgcn_mfma_f32_16x16x32_f16(k1, qa[1], tb, 0, 0, 0);
    }
    half2 a0 = pkrtz(__builtin_amdgcn_exp2f(ta[0]), __builtin_amdgcn_exp2f(ta[1]));
    half2 a1 = pkrtz(__builtin_amdgcn_exp2f(ta[2]), __builtin_amdgcn_exp2f(ta[3]));
    half2 b0 = pkrtz(__builtin_amdgcn_exp2f(tb[0]), __builtin_amdgcn_exp2f(tb[1]));
    half2 b1 = pkrtz(__builtin_amdgcn_exp2f(tb[2]), __builtin_amdgcn_exp2f(tb[3]));
    l_lane = __builtin_amdgcn_fdot2(a0, one2, l_lane, false);
    l_lane = __builtin_amdgcn_fdot2(a1, one2, l_lane, false);
    l_lane = __builtin_amdgcn_fdot2(b0, one2, l_lane, false);
    l_lane = __builtin_amdgcn_fdot2(b1, one2, l_lane, false);
    half4 pa = __builtin_shufflevector(a0, a1, 0, 1, 2, 3);
    half4 pb = __builtin_shufflevector(b0, b1, 0, 1, 2, 3);
    half8 pf = __builtin_shufflevector(pa, pb, 0, 4, 1, 5, 2, 6, 3, 7);
#pragma unroll
    for (int dt = 0; dt < 4; ++dt)
      o[dt] = __builtin_amdgcn_mfma_f32_16x16x32_f16(pf, vb[dt], o[dt], 0, 0, 0);
  };

  stage_k(0, 0);
  __syncthreads();
  stage_k(1, 1);

  half8 vA[4], vB[4];
  loadV(0, vA);

  const f16* bK0 = sK + (str * 2 + 0) * 2048;
  const f16* bK1 = sK + (str * 2 + 1) * 2048;

  for (int t = 0; t < 18; ++t) {
    // even tile kt0 = 2t: prefetch V(kt0+1), compute with vA
    loadV(2 * t + 1, vB);
    qk_pv(bK0, vA);
    __syncthreads();
    if (t < 17) {
      stage_k(2 * t + 2, 0);
      loadV(2 * t + 2, vA);  // prefetch V for next even tile
    }
    // odd tile kt1 = 2t+1: compute with vB
    qk_pv(bK1, vB);
    if (t < 17) {
      __syncthreads();
      stage_k(2 * t + 3, 1);
    }
  }

  // 2-way combine via LDS (reuse smem 16 KB: cO 12 KB + cL 768 B)
  __syncthreads();
  float* cO = (float*)smem;                    // [qgrp][dt][lane][4]
  float* cL = (float*)((char*)smem + 12288);   // [qgrp][lane]
  if (str == 1) {
    cL[qgrp * 64 + lane] = l_lane;
#pragma unroll
    for (int dt = 0; dt < 4; ++dt)
      *(floatx4*)&cO[((qgrp * 4 + dt) * 64 + lane) * 4] = o[dt];
  }
  __syncthreads();
  if (str == 0) {
    l_lane += cL[qgrp * 64 + lane];
#pragma unroll
    for (int dt = 0; dt < 4; ++dt)
      o[dt] += *(const floatx4*)&cO[((qgrp * 4 + dt) * 64 + lane) * 4];

    l_lane += __shfl_xor(l_lane, 16, 64);
    l_lane += __shfl_xor(l_lane, 32, 64);
    float inv[4];
#pragma unroll
    for (int r = 0; r < 4; ++r) {
      float lr = __shfl(l_lane, quad * 4 + r, 64);
      inv[r] = 1.f / lr;
    }
#pragma unroll
    for (int dt = 0; dt < 4; ++dt)
#pragma unroll
      for (int r = 0; r < 4; ++r) {
        int n_tok = m0 + qgrp * 16 + quad * 4 + r;
        int v = n_tok / 576, hw = n_tok % 576;
        int bb = g * 4 + v;
        int c = h * 64 + dt * 16 + l16;
        AOT[((size_t)bb * 576 + hw) * 512 + c] = (f16)(o[dt][r] * inv[r]);
      }
  }
}

// ---------------- proj GEMM: 64(o) x 128(t) tiles, grid 288 blocks ----------------
__global__ __launch_bounds__(256) void k_proj_gemm(const f16* __restrict__ AOT,
                                                   const f16* __restrict__ WP,
                                                   const float* __restrict__ bias,
                                                   float* __restrict__ out) {
  const int o0 = blockIdx.x * 64, t0 = blockIdx.y * 128;
  __shared__ alignas(16) f16 sA[64 * 64];   // [o][k]
  __shared__ alignas(16) f16 sB[128 * 64];  // [token][k]
  const int tid = threadIdx.x;
  const int wave = tid >> 6, lane = tid & 63, quad = lane >> 4, l16 = lane & 15;
  const int msub = (wave & 1) * 32, nsub = (wave >> 1) * 64;
  const floatx4 fzero = {0.f, 0.f, 0.f, 0.f};
  floatx4 acc[2][4];
  for (int i = 0; i < 2; ++i)
    for (int j = 0; j < 4; ++j) acc[i][j] = fzero;

  for (int k0 = 0; k0 < 512; k0 += 64) {
    __syncthreads();
    for (int p = 0; p < 2; ++p) {
      int e = p * 256 + tid;
      int row = e >> 3, colb = e & 7;
      async_cp16((const char*)WP + ((size_t)(o0 + row) * 512 + k0 + colb * 8) * 2,
                 (char*)sA + e * 16);
    }
    for (int p = 0; p < 4; ++p) {
      int e = p * 256 + tid;
      int row = e >> 3, colb = e & 7;
      async_cp16((const char*)AOT + ((size_t)(t0 + row) * 512 + k0 + colb * 8) * 2,
                 (char*)sB + e * 16);
    }
    __syncthreads();
    for (int f = 0; f < 2; ++f) {
      half8 a[2], bfr[4];
      for (int ms = 0; ms < 2; ++ms)
        a[ms] = *(const half8*)&sA[(msub + ms * 16 + l16) * 64 + f * 32 + quad * 8];
      for (int ns = 0; ns < 4; ++ns)
        bfr[ns] = *(const half8*)&sB[(nsub + ns * 16 + l16) * 64 + f * 32 + quad * 8];
      for (int ms = 0; ms < 2; ++ms)
        for (int ns = 0; ns < 4; ++ns)
          acc[ms][ns] =
              __builtin_amdgcn_mfma_f32_16x16x32_f16(a[ms], bfr[ns], acc[ms][ns], 0, 0, 0);
    }
  }
  for (int ms = 0; ms < 2; ++ms) {
    int o_row = o0 + msub + ms * 16 + quad * 4;
    for (int ns = 0; ns < 4; ++ns) {
      int t = t0 + nsub + ns * 16 + l16;
      int b = t / 576, hw = t % 576;
      for (int r = 0; r < 4; ++r) {
        int orow = o_row + r;
        out[(size_t)b * 294912 + (size_t)orow * 576 + hw] = acc[ms][ns][r] + bias[orow];
      }
    }
  }
}

extern "C" void kernel_launch(void* const* d_in, const int* in_sizes, int n_in,
                              void* d_out, int out_size, void* d_ws, size_t ws_size,
                              hipStream_t stream) {
  const float* x = (const float*)d_in[0];
  const float* wqkv = (const float*)d_in[1];
  const float* wproj = (const float*)d_in[2];
  const float* bias = (const float*)d_in[3];
  float* out = (float*)d_out;
  char* ws = (char*)d_ws;
  f16* XT = (f16*)(ws + 0);          // 4,718,592
  f16* WQ = (f16*)(ws + 4718592);    // 1,572,864
  f16* WP = (f16*)(ws + 6291456);    //   524,288
  f16* Qh = (f16*)(ws + 6815744);    // 4,718,592
  f16* Kh = (f16*)(ws + 11534336);   // 4,718,592
  f16* Vh = (f16*)(ws + 16252928);   // 4,718,592  ([gh][d][n'] key-interleaved)
  f16* AOT = (f16*)(ws + 20971520);  // 4,718,592

  k_prep<<<dim3(704), dim3(256), 0, stream>>>(x, XT, wqkv, wproj, WQ, WP);
  k_qkv_gemm<<<dim3(36, 12), dim3(256), 0, stream>>>(XT, WQ, Qh, Kh, Vh);
  k_attn<<<dim3(48, 16), dim3(384), 0, stream>>>(Qh, Kh, Vh, AOT);
  k_proj_gemm<<<dim3(8, 36), dim3(256), 0, stream>>>(AOT, WP, bias, out);
}

// Round 9
// 146.119 us; speedup vs baseline: 1.3224x; 1.3224x over previous
//
#include <hip/hip_runtime.h>
#include <stdint.h>

typedef _Float16 f16;
typedef _Float16 half8 __attribute__((ext_vector_type(8)));
typedef _Float16 half4 __attribute__((ext_vector_type(4)));
typedef _Float16 half2 __attribute__((ext_vector_type(2)));
typedef float floatx4 __attribute__((ext_vector_type(4)));

#define LOG2E 1.44269504088896340736f

// async global->LDS, 16B per lane. LDS dest must be wave-uniform base + lane*16.
__device__ __forceinline__ void async_cp16(const void* g, void* l) {
  __builtin_amdgcn_global_load_lds((const __attribute__((address_space(1))) void*)g,
                                   (__attribute__((address_space(3))) void*)l, 16, 0, 0);
}

// cvt_pkrtz returns __fp16x2; bit-cast to our _Float16-based half2.
__device__ __forceinline__ half2 pkrtz(float a, float b) {
  return __builtin_bit_cast(half2, __builtin_amdgcn_cvt_pkrtz(a, b));
}

// ---------------- fused prep: x transpose->fp16 + weight convert ----------------
__global__ __launch_bounds__(256) void k_prep(const float* __restrict__ x,
                                              f16* __restrict__ XT,
                                              const float* __restrict__ wqkv,
                                              const float* __restrict__ wproj,
                                              f16* __restrict__ WQ, f16* __restrict__ WP) {
  __shared__ f16 sT[64][72];
  const int bid = blockIdx.x;
  const int tid = threadIdx.x;
  if (bid < 576) {
    const int hw0 = (bid % 9) * 64, c0 = ((bid / 9) & 7) * 64, b = bid / 72;
    const int cc = tid >> 6, hwc = tid & 63;
    const float* xb = x + (size_t)b * 294912;
    for (int i = 0; i < 16; ++i) {
      int c = c0 + i * 4 + cc;
      sT[hwc][i * 4 + cc] = (f16)xb[c * 576 + hw0 + hwc];
    }
    __syncthreads();
    const int c_c = tid & 63, rr = tid >> 6;
    f16* xtb = XT + ((size_t)b * 576 + hw0) * 512 + c0;
    for (int j = 0; j < 16; ++j) {
      int r = j * 4 + rr;
      xtb[(size_t)r * 512 + c_c] = sT[r][c_c];
    }
  } else {
    const float SCALE_Q = 0.125f * LOG2E;
    const int total1 = 1536 * 512, total2 = 512 * 512;
    for (int idx = (bid - 576) * 256 + tid; idx < total1 + total2; idx += 128 * 256) {
      if (idx < total1) {
        int row = idx >> 9;
        float v = wqkv[idx];
        if ((row % 192) < 64) v *= SCALE_Q;
        WQ[idx] = (f16)v;
      } else {
        WP[idx - total1] = (f16)wproj[idx - total1];
      }
    }
  }
}

// ---------------- QKV GEMM: D[t][row] = XT[t][:] . WQ[row][:] ----------------
// Vh written KEY-INTERLEAVED within each 32-key group: position p = 2*(k&15) | (k>>4),
// so a 16B chunk c delivers keys {4c..4c+3} x {grp0,grp1} — the k-slot permutation
// consumed consistently by k_attn's PV 16x16x32 (A and B agree). Verified R6/R7.
__global__ __launch_bounds__(256) void k_qkv_gemm(const f16* __restrict__ XT,
                                                  const f16* __restrict__ WQ,
                                                  f16* __restrict__ Qh, f16* __restrict__ Kh,
                                                  f16* __restrict__ Vh) {
  const int t0 = blockIdx.x * 128, n0 = blockIdx.y * 128;
  __shared__ alignas(16) f16 smem[2 * 128 * 64];
  f16* sA = smem;
  f16* sB = smem + 128 * 64;
  const int tid = threadIdx.x;
  const int wave = tid >> 6, lane = tid & 63, quad = lane >> 4, l16 = lane & 15;
  const int msub = (wave & 1) * 64, nsub = (wave >> 1) * 64;
  const floatx4 fzero = {0.f, 0.f, 0.f, 0.f};
  floatx4 acc[4][4];
  for (int i = 0; i < 4; ++i)
    for (int j = 0; j < 4; ++j) acc[i][j] = fzero;

  for (int k0 = 0; k0 < 512; k0 += 64) {
    __syncthreads();
    for (int p = 0; p < 4; ++p) {
      int e = p * 256 + tid;
      int row = e >> 3, colb = e & 7;
      async_cp16((const char*)XT + ((size_t)(t0 + row) * 512 + k0 + colb * 8) * 2,
                 (char*)sA + e * 16);
      async_cp16((const char*)WQ + ((size_t)(n0 + row) * 512 + k0 + colb * 8) * 2,
                 (char*)sB + e * 16);
    }
    __syncthreads();
    for (int f = 0; f < 2; ++f) {
      half8 a[4], bfr[4];
      for (int ms = 0; ms < 4; ++ms)
        a[ms] = *(const half8*)&sA[(msub + ms * 16 + l16) * 64 + f * 32 + quad * 8];
      for (int ns = 0; ns < 4; ++ns)
        bfr[ns] = *(const half8*)&sB[(nsub + ns * 16 + l16) * 64 + f * 32 + quad * 8];
      for (int ms = 0; ms < 4; ++ms)
        for (int ns = 0; ns < 4; ++ns)
          acc[ms][ns] =
              __builtin_amdgcn_mfma_f32_16x16x32_f16(a[ms], bfr[ns], acc[ms][ns], 0, 0, 0);
    }
  }
  for (int ms = 0; ms < 4; ++ms) {
    int tbase = t0 + msub + ms * 16 + quad * 4;
    for (int ns = 0; ns < 4; ++ns) {
      int row = n0 + nsub + ns * 16 + l16;
      int h = row / 192, rr2 = row % 192;
      int sel = rr2 >> 6, d = rr2 & 63;
      if (sel == 2) continue;
      for (int r = 0; r < 4; ++r) {
        int t = tbase + r;
        int b = t / 576, hw = t % 576;
        int g = b >> 2, v = b & 3;
        int n = v * 576 + hw;
        int gh = g * 8 + h;
        f16 hv = (f16)acc[ms][ns][r];
        size_t idx = ((size_t)gh * 2304 + n) * 64 + d;
        if (sel == 0)
          Qh[idx] = hv;
        else
          Kh[idx] = hv;
      }
    }
  }
  const int r0 = n0 % 192;
  if (r0 != 0) {
    const int vloc = (r0 == 128) ? 0 : 64;
    const int h = (n0 + vloc) / 192;
    f16* sVT = smem;
    __syncthreads();
    if ((wave >> 1) == (vloc >> 6)) {
      for (int ms = 0; ms < 4; ++ms) {
        int tok = msub + ms * 16 + quad * 4;
        for (int ns = 0; ns < 4; ++ns) {
          int d = ns * 16 + l16;
          half4 hv;
          for (int r = 0; r < 4; ++r) hv[r] = (f16)acc[ms][ns][r];
          *(half4*)&sVT[d * 136 + tok] = hv;
        }
      }
    }
    __syncthreads();
    // interleaved V write: 32-token groups (576%32==0 -> no b-straddle)
    for (int pss = 0; pss < 4; ++pss) {
      int d = pss * 16 + (tid >> 4);
      int sub = tid & 15, gg = sub >> 2, u = sub & 3;
      int t = t0 + gg * 32;
      int b = t / 576, hw = t - b * 576;
      int gh = (b >> 2) * 8 + h, nb = (b & 3) * 576 + hw;
      half4 va = *(const half4*)&sVT[d * 136 + gg * 32 + u * 4];
      half4 vb2 = *(const half4*)&sVT[d * 136 + gg * 32 + 16 + u * 4];
      half8 w = __builtin_shufflevector(va, vb2, 0, 4, 1, 5, 2, 6, 3, 7);
      *(half8*)(Vh + (size_t)gh * 147456 + (size_t)d * 2304 + nb + u * 8) = w;
    }
  }
}

// ---------------- flash attention: 48 queries/block, 6 waves, key-split 2-way ----
// grid = 48 x 16 = 768 blocks = exactly 3/CU, 18 waves/CU uniform (R3 skeleton).
// K: LDS-staged (R3-verified: swizzled, dbuf, barrier/kt). V: LDS-staged in the
// INTERLEAVED layout (R6-verified math) -> one b128 read + one mfma 16x16x32 per dt
// (vs R3's 2x b64 + 2x 16x16x16). Softmax via pkrtz+fdot2 (R6-verified).
// LDS 32 KB. str 1 dumps unnormalized O,l; str 0 combines + normalizes.
__global__ __launch_bounds__(384, 4) void k_attn(const f16* __restrict__ Qh,
                                                 const f16* __restrict__ Kh,
                                                 const f16* __restrict__ Vh,
                                                 f16* __restrict__ AOT) {
  const int mt = blockIdx.x, gh = blockIdx.y;
  const int m0 = mt * 48;
  const int g = gh >> 3, h = gh & 7;
  const f16* Qg = Qh + (size_t)gh * 147456;  // [n][d]
  const f16* Kg = Kh + (size_t)gh * 147456;  // [n][d]
  const f16* Vg = Vh + (size_t)gh * 147456;  // [d][n'] key-interleaved
  __shared__ alignas(16) f16 smem[16384];    // 32 KB
  f16* sK = smem;                            // [str 2][buf 2][32*64]  (4 KB tiles)
  f16* sV = smem + 8192;                     // [str 2][buf 2][64*32]  (4 KB tiles)
  const int tid = threadIdx.x;
  const int wave = tid >> 6, lane = tid & 63, quad = lane >> 4, l16 = lane & 15;
  const int str = wave & 1, qgrp = wave >> 1;
  const floatx4 fzero = {0.f, 0.f, 0.f, 0.f};
  const int sw = l16 & 7;
  const int vsw = (l16 >> 1) & 3;
  const half2 one2 = {(f16)1.f, (f16)1.f};

  // stage 32-key K and V tiles for both streams into buf (1024 cp16 units / 384 thr).
  // K tile [32 key][64 d]: 128B rows, source pre-swizzle cb ^ (row&7).
  // V tile [64 d][32 key interleaved]: 64B rows, source pre-swizzle pc ^ ((row>>1)&3);
  // read side applies the same XOR -> cancels (both-sides rule).
  auto stage_kv = [&](int ktile, int buf) {
#pragma unroll
    for (int p = 0; p < 3; ++p) {
      int idx = p * 384 + tid;
      if (idx < 1024) {
        int isV = idx >= 512;
        int rem = idx & 511;
        int st = rem >> 8, unit = rem & 255;
        if (!isV) {
          int row = unit >> 3, cb = unit & 7;
          async_cp16(
              Kg + (size_t)(st * 1152 + ktile * 32 + row) * 64 + ((cb ^ (row & 7)) << 3),
              (char*)(sK + (st * 2 + buf) * 2048) + unit * 16);
        } else {
          int row = unit >> 2, pc = unit & 3;
          async_cp16(Vg + (size_t)row * 2304 + st * 1152 + ktile * 32 +
                         ((pc ^ ((row >> 1) & 3)) << 3),
                     (char*)(sV + (st * 2 + buf) * 2048) + unit * 16);
        }
      }
    }
  };

  // Q direct to registers (B-frag: col=l16, k=quad*8+j / +32)
  half8 qa[2];
  {
    int qrow = m0 + qgrp * 16 + l16;
    qa[0] = *(const half8*)(Qg + (size_t)qrow * 64 + quad * 8);
    qa[1] = *(const half8*)(Qg + (size_t)qrow * 64 + 32 + quad * 8);
  }

  stage_kv(0, 0);
  __syncthreads();
  stage_kv(1, 1);

  float l_lane = 0.f;
  floatx4 o[4];
  for (int dt = 0; dt < 4; ++dt) o[dt] = fzero;

  for (int kt = 0; kt < 36; ++kt) {
    const f16* bK = sK + (str * 2 + (kt & 1)) * 2048;
    const f16* bV = sV + (str * 2 + (kt & 1)) * 2048;

    // V fragments: one b128 per dt (bank-uniform under the chunk swizzle)
    half8 vb[4];
#pragma unroll
    for (int dt = 0; dt < 4; ++dt)
      vb[dt] = *(const half8*)&bV[(dt * 16 + l16) * 32 + ((quad ^ vsw) << 3)];

    // QK for both 16-key halves (independent chains)
    floatx4 ta, tb;
    {
      half8 k0 = *(const half8*)&bK[l16 * 64 + ((quad ^ sw) << 3)];
      half8 k1 = *(const half8*)&bK[l16 * 64 + (((4 + quad) ^ sw) << 3)];
      ta = __builtin_amdgcn_mfma_f32_16x16x32_f16(k0, qa[0], fzero, 0, 0, 0);
      ta = __builtin_amdgcn_mfma_f32_16x16x32_f16(k1, qa[1], ta, 0, 0, 0);
    }
    {
      half8 k0 = *(const half8*)&bK[(16 + l16) * 64 + ((quad ^ sw) << 3)];
      half8 k1 = *(const half8*)&bK[(16 + l16) * 64 + (((4 + quad) ^ sw) << 3)];
      tb = __builtin_amdgcn_mfma_f32_16x16x32_f16(k0, qa[0], fzero, 0, 0, 0);
      tb = __builtin_amdgcn_mfma_f32_16x16x32_f16(k1, qa[1], tb, 0, 0, 0);
    }
    half2 a0 = pkrtz(__builtin_amdgcn_exp2f(ta[0]), __builtin_amdgcn_exp2f(ta[1]));
    half2 a1 = pkrtz(__builtin_amdgcn_exp2f(ta[2]), __builtin_amdgcn_exp2f(ta[3]));
    half2 b0 = pkrtz(__builtin_amdgcn_exp2f(tb[0]), __builtin_amdgcn_exp2f(tb[1]));
    half2 b1 = pkrtz(__builtin_amdgcn_exp2f(tb[2]), __builtin_amdgcn_exp2f(tb[3]));
    l_lane = __builtin_amdgcn_fdot2(a0, one2, l_lane, false);
    l_lane = __builtin_amdgcn_fdot2(a1, one2, l_lane, false);
    l_lane = __builtin_amdgcn_fdot2(b0, one2, l_lane, false);
    l_lane = __builtin_amdgcn_fdot2(b1, one2, l_lane, false);
    half4 pa = __builtin_shufflevector(a0, a1, 0, 1, 2, 3);
    half4 pb = __builtin_shufflevector(b0, b1, 0, 1, 2, 3);
    half8 pf = __builtin_shufflevector(pa, pb, 0, 4, 1, 5, 2, 6, 3, 7);

#pragma unroll
    for (int dt = 0; dt < 4; ++dt)
      o[dt] = __builtin_amdgcn_mfma_f32_16x16x32_f16(pf, vb[dt], o[dt], 0, 0, 0);

    if (kt < 35) {
      __syncthreads();
      if (kt + 2 < 36) stage_kv(kt + 2, kt & 1);
    }
  }

  // 2-way combine via LDS (reuse smem: cO 12 KB + cL 768 B)
  __syncthreads();
  float* cO = (float*)smem;                   // [qgrp][dt][lane][4]
  float* cL = (float*)((char*)smem + 24576);  // [qgrp][lane]
  if (str == 1) {
    cL[qgrp * 64 + lane] = l_lane;
#pragma unroll
    for (int dt = 0; dt < 4; ++dt)
      *(floatx4*)&cO[((qgrp * 4 + dt) * 64 + lane) * 4] = o[dt];
  }
  __syncthreads();
  if (str == 0) {
    l_lane += cL[qgrp * 64 + lane];
#pragma unroll
    for (int dt = 0; dt < 4; ++dt)
      o[dt] += *(const floatx4*)&cO[((qgrp * 4 + dt) * 64 + lane) * 4];

    l_lane += __shfl_xor(l_lane, 16, 64);
    l_lane += __shfl_xor(l_lane, 32, 64);
    float inv[4];
#pragma unroll
    for (int r = 0; r < 4; ++r) {
      float lr = __shfl(l_lane, quad * 4 + r, 64);
      inv[r] = 1.f / lr;
    }
#pragma unroll
    for (int dt = 0; dt < 4; ++dt)
#pragma unroll
      for (int r = 0; r < 4; ++r) {
        int n_tok = m0 + qgrp * 16 + quad * 4 + r;
        int v = n_tok / 576, hw = n_tok % 576;
        int bb = g * 4 + v;
        int c = h * 64 + dt * 16 + l16;
        AOT[((size_t)bb * 576 + hw) * 512 + c] = (f16)(o[dt][r] * inv[r]);
      }
  }
}

// ---------------- proj GEMM: 64(o) x 128(t) tiles, grid 288 blocks ----------------
__global__ __launch_bounds__(256) void k_proj_gemm(const f16* __restrict__ AOT,
                                                   const f16* __restrict__ WP,
                                                   const float* __restrict__ bias,
                                                   float* __restrict__ out) {
  const int o0 = blockIdx.x * 64, t0 = blockIdx.y * 128;
  __shared__ alignas(16) f16 sA[64 * 64];   // [o][k]
  __shared__ alignas(16) f16 sB[128 * 64];  // [token][k]
  const int tid = threadIdx.x;
  const int wave = tid >> 6, lane = tid & 63, quad = lane >> 4, l16 = lane & 15;
  const int msub = (wave & 1) * 32, nsub = (wave >> 1) * 64;
  const floatx4 fzero = {0.f, 0.f, 0.f, 0.f};
  floatx4 acc[2][4];
  for (int i = 0; i < 2; ++i)
    for (int j = 0; j < 4; ++j) acc[i][j] = fzero;

  for (int k0 = 0; k0 < 512; k0 += 64) {
    __syncthreads();
    for (int p = 0; p < 2; ++p) {
      int e = p * 256 + tid;
      int row = e >> 3, colb = e & 7;
      async_cp16((const char*)WP + ((size_t)(o0 + row) * 512 + k0 + colb * 8) * 2,
                 (char*)sA + e * 16);
    }
    for (int p = 0; p < 4; ++p) {
      int e = p * 256 + tid;
      int row = e >> 3, colb = e & 7;
      async_cp16((const char*)AOT + ((size_t)(t0 + row) * 512 + k0 + colb * 8) * 2,
                 (char*)sB + e * 16);
    }
    __syncthreads();
    for (int f = 0; f < 2; ++f) {
      half8 a[2], bfr[4];
      for (int ms = 0; ms < 2; ++ms)
        a[ms] = *(const half8*)&sA[(msub + ms * 16 + l16) * 64 + f * 32 + quad * 8];
      for (int ns = 0; ns < 4; ++ns)
        bfr[ns] = *(const half8*)&sB[(nsub + ns * 16 + l16) * 64 + f * 32 + quad * 8];
      for (int ms = 0; ms < 2; ++ms)
        for (int ns = 0; ns < 4; ++ns)
          acc[ms][ns] =
              __builtin_amdgcn_mfma_f32_16x16x32_f16(a[ms], bfr[ns], acc[ms][ns], 0, 0, 0);
    }
  }
  for (int ms = 0; ms < 2; ++ms) {
    int o_row = o0 + msub + ms * 16 + quad * 4;
    for (int ns = 0; ns < 4; ++ns) {
      int t = t0 + nsub + ns * 16 + l16;
      int b = t / 576, hw = t % 576;
      for (int r = 0; r < 4; ++r) {
        int orow = o_row + r;
        out[(size_t)b * 294912 + (size_t)orow * 576 + hw] = acc[ms][ns][r] + bias[orow];
      }
    }
  }
}

extern "C" void kernel_launch(void* const* d_in, const int* in_sizes, int n_in,
                              void* d_out, int out_size, void* d_ws, size_t ws_size,
                              hipStream_t stream) {
  const float* x = (const float*)d_in[0];
  const float* wqkv = (const float*)d_in[1];
  const float* wproj = (const float*)d_in[2];
  const float* bias = (const float*)d_in[3];
  float* out = (float*)d_out;
  char* ws = (char*)d_ws;
  f16* XT = (f16*)(ws + 0);          // 4,718,592
  f16* WQ = (f16*)(ws + 4718592);    // 1,572,864
  f16* WP = (f16*)(ws + 6291456);    //   524,288
  f16* Qh = (f16*)(ws + 6815744);    // 4,718,592
  f16* Kh = (f16*)(ws + 11534336);   // 4,718,592
  f16* Vh = (f16*)(ws + 16252928);   // 4,718,592  ([gh][d][n'] key-interleaved)
  f16* AOT = (f16*)(ws + 20971520);  // 4,718,592

  k_prep<<<dim3(704), dim3(256), 0, stream>>>(x, XT, wqkv, wproj, WQ, WP);
  k_qkv_gemm<<<dim3(36, 12), dim3(256), 0, stream>>>(XT, WQ, Qh, Kh, Vh);
  k_attn<<<dim3(48, 16), dim3(384), 0, stream>>>(Qh, Kh, Vh, AOT);
  k_proj_gemm<<<dim3(8, 36), dim3(256), 0, stream>>>(AOT, WP, bias, out);
}